// Round 1
// baseline (52.825 us; speedup 1.0000x reference)
//
#include <hip/hip_runtime.h>
#include <math.h>

// ---------------------------------------------------------------------------
// ZBL repulsion:
//   per-edge: d = ||disp||; switch(d); arg = d*(za_i+za_j)/|a|;
//             phi = sum_k c_k * exp(-e_k*arg - max_k(-e_k*arg))   (quirk kept)
//             rep = 0.5*z_i*z_j/d * max(phi,1e-30)*max(sw,1e-30)*batch_mask
//   Erep[i] = segment_sum(rep, idx_i) * atom_mask
// ---------------------------------------------------------------------------

// Kernel 1: per-atom precompute (z, z^|a_exp|) table + zero output + scalar
// constants (softmax(|phi_c|), |phi_e|, 1/|a_coef|) via thread (0,0).
__global__ __launch_bounds__(256) void zbl_prep_kernel(
    const float* __restrict__ z, const float* __restrict__ a_coef,
    const float* __restrict__ a_exp, const float* __restrict__ phi_c,
    const float* __restrict__ phi_e, float2* __restrict__ tab,
    float* __restrict__ out, float* __restrict__ consts, int n_atoms) {
  int n = blockIdx.x * blockDim.x + threadIdx.x;
  if (n < n_atoms) {
    float zi = z[n];
    float ae = fabsf(a_exp[0]);
    tab[n] = make_float2(zi, powf(zi, ae));
    out[n] = 0.0f;
  }
  if (blockIdx.x == 0 && threadIdx.x == 0) {
    float c[4];
    float m = -1e30f;
    for (int k = 0; k < 4; ++k) { c[k] = fabsf(phi_c[k]); m = fmaxf(m, c[k]); }
    float s = 0.0f;
    for (int k = 0; k < 4; ++k) { c[k] = expf(c[k] - m); s += c[k]; }
    float inv_s = 1.0f / s;
    for (int k = 0; k < 4; ++k) consts[k] = c[k] * inv_s;       // softmax coeffs
    for (int k = 0; k < 4; ++k) consts[4 + k] = fabsf(phi_e[k]); // |exponents|
    consts[8] = 1.0f / fabsf(a_coef[0]);                         // 1/|a|
  }
}

// Kernel 2: per-edge repulsion + wave-segmented reduction + atomicAdd.
__global__ __launch_bounds__(256) void zbl_edge_kernel(
    const float* __restrict__ disp, const int* __restrict__ idx_i,
    const int* __restrict__ idx_j, const float* __restrict__ bmask,
    const float2* __restrict__ tab, const float* __restrict__ consts,
    float* __restrict__ out, int n_edges) {
  int e = blockIdx.x * blockDim.x + threadIdx.x;
  int lane = threadIdx.x & 63;

  float v = 0.0f;
  int key = -1;
  if (e < n_edges) {
    int i = idx_i[e];
    int j = idx_j[e];
    float dx = disp[3 * e + 0];
    float dy = disp[3 * e + 1];
    float dz = disp[3 * e + 2];
    float d = sqrtf(dx * dx + dy * dy + dz * dz);
    d = fmaxf(d, 1e-10f);

    // smooth switch between CUTON=4 and CUTOFF=5
    float x = 5.0f - d;  // (CUTOFF - d) / (CUTOFF - CUTON), denom == 1
    float poly = ((6.0f * x - 15.0f) * x + 10.0f) * x * x * x;
    float sw = (d < 4.0f) ? 1.0f : ((d >= 5.0f) ? 0.0f : poly);

    float2 ti = tab[i];
    float2 tj = tab[j];
    float denom = fmaxf(ti.y + tj.y, 1e-10f);
    float arg = d * denom * consts[8];

    float e0 = consts[4], e1 = consts[5], e2 = consts[6], e3 = consts[7];
    float l0 = -e0 * arg, l1 = -e1 * arg, l2 = -e2 * arg, l3 = -e3 * arg;
    float m = fmaxf(fmaxf(l0, l1), fmaxf(l2, l3));
    float phi = consts[0] * expf(l0 - m) + consts[1] * expf(l1 - m) +
                consts[2] * expf(l2 - m) + consts[3] * expf(l3 - m);

    float rep = 0.5f * ti.x * tj.x / d * fmaxf(phi, 1e-30f) *
                fmaxf(sw, 1e-30f) * bmask[e];
    v = rep;
    key = i;
  }

  // Wave-level segmented suffix sum over equal adjacent keys (idx_i sorted,
  // but correctness does not depend on sortedness: each run-head emits one
  // atomic with its run's sum).
  for (int off = 1; off < 64; off <<= 1) {
    float v2 = __shfl_down(v, off, 64);
    int k2 = __shfl_down(key, off, 64);
    if (lane + off < 64 && k2 == key) v += v2;
  }
  int kup = __shfl_up(key, 1, 64);
  if (key >= 0 && (lane == 0 || kup != key)) atomicAdd(&out[key], v);
}

// Kernel 3: apply atom_mask.
__global__ __launch_bounds__(256) void zbl_mask_kernel(
    const float* __restrict__ mask, float* __restrict__ out, int n_atoms) {
  int n = blockIdx.x * blockDim.x + threadIdx.x;
  if (n < n_atoms) out[n] *= mask[n];
}

extern "C" void kernel_launch(void* const* d_in, const int* in_sizes, int n_in,
                              void* d_out, int out_size, void* d_ws,
                              size_t ws_size, hipStream_t stream) {
  const float* atomic_numbers = (const float*)d_in[0];
  const float* disp           = (const float*)d_in[1];
  const int*   idx_i          = (const int*)d_in[2];
  const int*   idx_j          = (const int*)d_in[3];
  const float* atom_mask      = (const float*)d_in[4];
  // d_in[5] = batch_segments (unused), d_in[7] = batch_size (unused)
  const float* bmask          = (const float*)d_in[6];
  const float* a_coef         = (const float*)d_in[8];
  const float* a_exp          = (const float*)d_in[9];
  const float* phi_c          = (const float*)d_in[10];
  const float* phi_e          = (const float*)d_in[11];

  int n_atoms = in_sizes[0];
  int n_edges = in_sizes[2];

  float* out = (float*)d_out;
  float2* tab = (float2*)d_ws;
  float* consts = (float*)((char*)d_ws + (size_t)n_atoms * sizeof(float2));

  int atom_blocks = (n_atoms + 255) / 256;
  int edge_blocks = (n_edges + 255) / 256;

  zbl_prep_kernel<<<atom_blocks, 256, 0, stream>>>(
      atomic_numbers, a_coef, a_exp, phi_c, phi_e, tab, out, consts, n_atoms);
  zbl_edge_kernel<<<edge_blocks, 256, 0, stream>>>(
      disp, idx_i, idx_j, bmask, tab, consts, out, n_edges);
  zbl_mask_kernel<<<atom_blocks, 256, 0, stream>>>(atom_mask, out, n_atoms);
}